// Round 10
// baseline (311.261 us; speedup 1.0000x reference)
//
#include <hip/hip_runtime.h>
#include <math.h>

#define Bb 128
#define Tt 1024
#define Ll 96

typedef float v2f __attribute__((ext_vector_type(2)));
typedef float v4f __attribute__((ext_vector_type(4)));

// One block = one batch = TWO waves, independent chain halves (round 7):
//   wave 0 (forward):  Q_t = (E^T Q_{t-1}) o w_t * 2^-k,  t = 1..511
//   wave 1 (backward): V-chain from t=1023 down to 512
// Meeting: log_norm = log(V_511 . Q_511) + (Dk_f + Dk_b)*ln2.  512 steps.
//
// Round-10 changes vs round 9 (both attack exposed serial LDS latency):
//  * Cross-iteration preload: first 8 ds_read_b128 (P0..P7) issue at the
//    BOTTOM of each iteration right after the ds_write (same-wave DS pipe is
//    in-order, so they see the write). Bookkeeping + backedge overlap the
//    ~120cy LDS latency; the 16 remaining reads issue at top while chunks
//    0-7 compute.
//  * k extracted from P0.x (stored element 0, identical in all lanes) with
//    per-lane Dk += k — removes the readfirstlane->SALU chain from the
//    serial path. 2^-k rescale is an EXACT power of 2 and accumulation
//    order is unchanged -> absmax must remain 0.0.
__global__ __launch_bounds__(128, 1)
__attribute__((amdgpu_waves_per_eu(1)))
void crf_fwd_kernel(
    const float* __restrict__ inputs,      // (B, T, L) fp32
    const int*   __restrict__ labels_idx,  // (B, T) int32
    const float* __restrict__ trans,       // (L, L) fp32
    float*       __restrict__ out)         // (B, 1) fp32
{
    const int b    = blockIdx.x;
    const int tid  = threadIdx.x;                    // 0..127
    const int wave = tid >> 6;
    const int i    = tid & 63;                       // lane
    const int col  = (2 * i < Ll) ? 2 * i : (Ll - 2); // clamp lanes 48..63

    __shared__ __align__(16) float qbuf[2][Ll];  // fwd double buffer (parity)
    __shared__ __align__(16) float sbuf[Ll];     // bwd single buffer
    __shared__ __align__(16) float uex[Ll];      // backward V_511
    __shared__ float wps[2];                     // per-wave score partials
    __shared__ int   dks[2];                     // per-wave Dk

    const float* xbase = inputs + (size_t)b * Tt * Ll;

    // ---- point_score + trans_score, split across both waves ----
    float ps = 0.f;
    {
        const int* lb = labels_idx + b * Tt;
        #pragma unroll 4
        for (int t = tid; t < Tt; t += 128) {
            int i0 = lb[t];
            ps += xbase[t * Ll + i0];
            if (t < Tt - 1) ps += trans[i0 * Ll + lb[t + 1]];
        }
        #pragma unroll
        for (int off = 32; off; off >>= 1) ps += __shfl_xor(ps, off, 64);
        if (i == 0) wps[wave] = ps;
    }

#define EROWS(X) \
    X(0)  X(1)  X(2)  X(3)  X(4)  X(5)  X(6)  X(7)  X(8)  X(9)  X(10) X(11) \
    X(12) X(13) X(14) X(15) X(16) X(17) X(18) X(19) X(20) X(21) X(22) X(23) \
    X(24) X(25) X(26) X(27) X(28) X(29) X(30) X(31) X(32) X(33) X(34) X(35) \
    X(36) X(37) X(38) X(39) X(40) X(41) X(42) X(43) X(44) X(45) X(46) X(47) \
    X(48) X(49) X(50) X(51) X(52) X(53) X(54) X(55) X(56) X(57) X(58) X(59) \
    X(60) X(61) X(62) X(63) X(64) X(65) X(66) X(67) X(68) X(69) X(70) X(71) \
    X(72) X(73) X(74) X(75) X(76) X(77) X(78) X(79) X(80) X(81) X(82) X(83) \
    X(84) X(85) X(86) X(87) X(88) X(89) X(90) X(91) X(92) X(93) X(94) X(95)

#define EDECL(n) v2f EE##n;

// one chunk: a 16B quad (already in regs) feeds 4 pk-FMAs via splats.
#define CHUNK(q4, n0, n1, n2, n3) { \
        acc0 += (v2f){q4.x, q4.x} * EE##n0; \
        acc1 += (v2f){q4.y, q4.y} * EE##n1; \
        acc2 += (v2f){q4.z, q4.z} * EE##n2; \
        acc3 += (v2f){q4.w, q4.w} * EE##n3; }

// chunks 8..23 read at top (Q8..Q23), chunks 0..7 use preloaded P0..P7.
#define MATVEC_BODY(qp) \
        v4f Q8  = qp[8],  Q9  = qp[9],  Q10 = qp[10], Q11 = qp[11], \
            Q12 = qp[12], Q13 = qp[13], Q14 = qp[14], Q15 = qp[15]; \
        v4f Q16 = qp[16], Q17 = qp[17], Q18 = qp[18], Q19 = qp[19], \
            Q20 = qp[20], Q21 = qp[21], Q22 = qp[22], Q23 = qp[23]; \
        CHUNK(P0,  0,  1,  2,  3)   CHUNK(P1,  4,  5,  6,  7)  \
        CHUNK(P2,  8,  9,  10, 11)  CHUNK(P3,  12, 13, 14, 15) \
        CHUNK(P4,  16, 17, 18, 19)  CHUNK(P5,  20, 21, 22, 23) \
        CHUNK(P6,  24, 25, 26, 27)  CHUNK(P7,  28, 29, 30, 31) \
        CHUNK(Q8,  32, 33, 34, 35)  CHUNK(Q9,  36, 37, 38, 39) \
        CHUNK(Q10, 40, 41, 42, 43)  CHUNK(Q11, 44, 45, 46, 47) \
        CHUNK(Q12, 48, 49, 50, 51)  CHUNK(Q13, 52, 53, 54, 55) \
        CHUNK(Q14, 56, 57, 58, 59)  CHUNK(Q15, 60, 61, 62, 63) \
        CHUNK(Q16, 64, 65, 66, 67)  CHUNK(Q17, 68, 69, 70, 71) \
        CHUNK(Q18, 72, 73, 74, 75)  CHUNK(Q19, 76, 77, 78, 79) \
        CHUNK(Q20, 80, 81, 82, 83)  CHUNK(Q21, 84, 85, 86, 87) \
        CHUNK(Q22, 88, 89, 90, 91)  CHUNK(Q23, 92, 93, 94, 95)

    v2f qv;                // this wave's two owned state elements
    int Dk = 0;

    if (wave == 0) {
        // ================= FORWARD: t = 1..511 =================
        EROWS(EDECL)
        // column layout: EE_n = {E[n][col], E[n][col+1]}
#define EINIT(n) { v2f r_ = *reinterpret_cast<const v2f*>(&trans[(n) * Ll + col]); \
                   EE##n = (v2f){__expf(r_.x), __expf(r_.y)}; \
                   asm volatile("" ::: "memory"); }
        EROWS(EINIT)
#undef EINIT

        v2f x0 = *reinterpret_cast<const v2f*>(&xbase[col]);
        qv = (v2f){__expf(x0.x), __expf(x0.y)};
        if (i < 48) *reinterpret_cast<v2f*>(&qbuf[0][col]) = qv;
        asm volatile("" ::: "memory");
        const v4f* q0p = reinterpret_cast<const v4f*>(&qbuf[0][0]);
        v4f P0 = q0p[0], P1 = q0p[1], P2 = q0p[2], P3 = q0p[3],
            P4 = q0p[4], P5 = q0p[5], P6 = q0p[6], P7 = q0p[7];

        v2f x1 = *reinterpret_cast<const v2f*>(&xbase[1 * Ll + col]);
        v2f ew = (v2f){__expf(x1.x), __expf(x1.y)};
        v2f x2 = *reinterpret_cast<const v2f*>(&xbase[2 * Ll + col]);
        v2f x3 = *reinterpret_cast<const v2f*>(&xbase[3 * Ll + col]);
        v2f x4 = *reinterpret_cast<const v2f*>(&xbase[4 * Ll + col]);
        v2f x5 = *reinterpret_cast<const v2f*>(&xbase[5 * Ll + col]);
        v2f x6 = *reinterpret_cast<const v2f*>(&xbase[6 * Ll + col]);
        v2f x7 = *reinterpret_cast<const v2f*>(&xbase[7 * Ll + col]);

        #pragma unroll 1
        for (int t = 1; t <= Tt / 2 - 1; ++t) {
            const int rp = (t - 1) & 1, wp = t & 1;
            // k from preloaded P0.x (= stored Q_{t-1}[0], wave-uniform)
            int k = ((__float_as_int(P0.x) >> 23) & 0xff) - 127;
            Dk += k;
            float r = __uint_as_float((unsigned)(127 - k) << 23); // exact 2^-k
            v2f w = ew * r;

            const v4f* qp = reinterpret_cast<const v4f*>(&qbuf[rp][0]);
            v2f acc0 = {0.f,0.f}, acc1 = {0.f,0.f};
            v2f acc2 = {0.f,0.f}, acc3 = {0.f,0.f};
            MATVEC_BODY(qp)
            qv = ((acc0 + acc1) + (acc2 + acc3)) * w;

            if (i < 48) *reinterpret_cast<v2f*>(&qbuf[wp][col]) = qv;
            asm volatile("" ::: "memory");
            // preload first 8 quads for step t+1 (hidden under bookkeeping)
            const v4f* qn = reinterpret_cast<const v4f*>(&qbuf[wp][0]);
            P0 = qn[0]; P1 = qn[1]; P2 = qn[2]; P3 = qn[3];
            P4 = qn[4]; P5 = qn[5]; P6 = qn[6]; P7 = qn[7];

            // off-path bookkeeping (overlaps the preload latency)
            ew = (v2f){__expf(x2.x), __expf(x2.y)};
            x2 = x3; x3 = x4; x4 = x5; x5 = x6; x6 = x7;
            int row = t + 7; if (row > Tt - 1) row = Tt - 1;
            x7 = *reinterpret_cast<const v2f*>(&xbase[row * Ll + col]);
        }
        if (i == 0) dks[0] = Dk;
    } else {
        // ================= BACKWARD: t = 1023..512 =================
        // row layout: EE_n = {E[col][n], E[col+1][n]}
        EROWS(EDECL)
#define EINIT(n) { EE##n = (v2f){__expf(trans[col * Ll + (n)]), \
                                 __expf(trans[(col + 1) * Ll + (n)])}; \
                   asm volatile("" ::: "memory"); }
        EROWS(EINIT)
#undef EINIT

        // s_1023 = V_1023 o w_1023 = exp(x_1023); k_0 = 0
        v2f xT = *reinterpret_cast<const v2f*>(&xbase[(Tt - 1) * Ll + col]);
        v2f s0 = (v2f){__expf(xT.x), __expf(xT.y)};
        if (i < 48) *reinterpret_cast<v2f*>(&sbuf[col]) = s0;
        asm volatile("" ::: "memory");
        const v4f* s0p = reinterpret_cast<const v4f*>(&sbuf[0]);
        v4f P0 = s0p[0], P1 = s0p[1], P2 = s0p[2], P3 = s0p[3],
            P4 = s0p[4], P5 = s0p[5], P6 = s0p[6], P7 = s0p[7];

        // queue: ew = exp(x_{t-1}); x2..x7 = rows t-2 .. t-7
        v2f xh = *reinterpret_cast<const v2f*>(&xbase[(Tt - 2) * Ll + col]);
        v2f ew = (v2f){__expf(xh.x), __expf(xh.y)};
        v2f x2 = *reinterpret_cast<const v2f*>(&xbase[(Tt - 3) * Ll + col]);
        v2f x3 = *reinterpret_cast<const v2f*>(&xbase[(Tt - 4) * Ll + col]);
        v2f x4 = *reinterpret_cast<const v2f*>(&xbase[(Tt - 5) * Ll + col]);
        v2f x5 = *reinterpret_cast<const v2f*>(&xbase[(Tt - 6) * Ll + col]);
        v2f x6 = *reinterpret_cast<const v2f*>(&xbase[(Tt - 7) * Ll + col]);
        v2f x7 = *reinterpret_cast<const v2f*>(&xbase[(Tt - 8) * Ll + col]);

        #pragma unroll 1
        for (int t = Tt - 1; t >= Tt / 2; --t) {
            // k from preloaded P0.x (= stored s_t[0], wave-uniform)
            int k = ((__float_as_int(P0.x) >> 23) & 0xff) - 127;
            Dk += k;
            float r = __uint_as_float((unsigned)(127 - k) << 23); // exact 2^-k

            const v4f* qp = reinterpret_cast<const v4f*>(&sbuf[0]);
            v2f acc0 = {0.f,0.f}, acc1 = {0.f,0.f};
            v2f acc2 = {0.f,0.f}, acc3 = {0.f,0.f};
            MATVEC_BODY(qp)
            qv = (acc0 + acc1) + (acc2 + acc3);     // V_{t-1} (stored scale)

            // bottom: write s_{t-1} = V_{t-1} o w_{t-1} * 2^-k
            v2f sw = qv * (ew * r);
            if (i < 48) *reinterpret_cast<v2f*>(&sbuf[col]) = sw;
            asm volatile("" ::: "memory");
            const v4f* sn = reinterpret_cast<const v4f*>(&sbuf[0]);
            P0 = sn[0]; P1 = sn[1]; P2 = sn[2]; P3 = sn[3];
            P4 = sn[4]; P5 = sn[5]; P6 = sn[6]; P7 = sn[7];

            // off-path bookkeeping (overlaps the preload latency)
            ew = (v2f){__expf(x2.x), __expf(x2.y)};
            x2 = x3; x3 = x4; x4 = x5; x5 = x6; x6 = x7;
            int row = t - 8; if (row < 0) row = 0;
            x7 = *reinterpret_cast<const v2f*>(&xbase[row * Ll + col]);
        }
        if (i < 48) *reinterpret_cast<v2f*>(&uex[col]) = qv;   // V_511
        if (i == 0) dks[1] = Dk;
    }
#undef MATVEC_BODY
#undef CHUNK
#undef EDECL
#undef EROWS

    __syncthreads();

    // ---- meeting point: log_norm = log(V_511 . Q_511) + (Dk_f+Dk_b)*ln2 ----
    if (wave == 0) {
        v2f u = (i < 48) ? *reinterpret_cast<const v2f*>(&uex[col]) : (v2f){0.f, 0.f};
        float d = (i < 48) ? (qv.x * u.x + qv.y * u.y) : 0.f;
        #pragma unroll
        for (int off = 32; off; off >>= 1) d += __shfl_xor(d, off, 64);
        if (i == 0) {
            double ln = (double)(dks[0] + dks[1]) * 0.6931471805599453
                      + log((double)d);
            out[b] = (float)(ln - (double)(wps[0] + wps[1]));
        }
    }
}

extern "C" void kernel_launch(void* const* d_in, const int* in_sizes, int n_in,
                              void* d_out, int out_size, void* d_ws, size_t ws_size,
                              hipStream_t stream) {
    const float* inputs     = (const float*)d_in[0];
    const int*   labels_idx = (const int*)d_in[1];
    const float* trans      = (const float*)d_in[2];
    float*       out        = (float*)d_out;

    crf_fwd_kernel<<<dim3(Bb), dim3(128), 0, stream>>>(inputs, labels_idx, trans, out);
}

// Round 11
// 289.080 us; speedup vs baseline: 1.0767x; 1.0767x over previous
//
#include <hip/hip_runtime.h>
#include <math.h>

#define Bb 128
#define Tt 1024
#define Ll 96
#define WS_STRIDE 200   // floats per batch in workspace

typedef float v2f __attribute__((ext_vector_type(2)));
typedef float v4f __attribute__((ext_vector_type(4)));

// 256 blocks x 1 wave: block < 128 runs the FORWARD half-chain of batch b,
// block >= 128 runs the BACKWARD half-chain (round 7 bidirectional split,
// 512 serial steps). Each chain now owns a full CU: no shared LDS pipe.
// Handoff via d_ws; a tiny combine kernel does the meeting-point math.
//
// Round-11 changes:
//  * backward Dk fix: the last iteration's k is added to Dk but applied only
//    to the never-read s_511 write -> subtract it after the loop (round 10
//    overcounted by k_512: absmax 32).
//  * pair-over-l FMAs: acc += {q.x,q.y} * {E[2p][c],E[2p+1][c]} - the q
//    operand is two adjacent VGPRs straight from ds_read_b128, no splats.
//  * fwd/bwd on separate CUs (own LDS pipe, own L1).
__global__ __launch_bounds__(64, 1)
__attribute__((amdgpu_waves_per_eu(1)))
void crf_scan_kernel(
    const float* __restrict__ inputs,      // (B, T, L) fp32
    const int*   __restrict__ labels_idx,  // (B, T) int32
    const float* __restrict__ trans,       // (L, L) fp32
    float*       __restrict__ ws)          // workspace: 128 x WS_STRIDE floats
{
    const int blk = blockIdx.x;
    const bool fw = (blk < Bb);
    const int b   = fw ? blk : (blk - Bb);
    const int i   = threadIdx.x;                     // 0..63
    const int col = (2 * i < Ll) ? 2 * i : (Ll - 2); // clamp lanes 48..63

    __shared__ __align__(16) float buf[2][Ll];       // state buffer(s)

    const float* xbase = inputs + (size_t)b * Tt * Ll;
    float* wsb = ws + (size_t)b * WS_STRIDE;

#define EPAIRS(X) \
    X(0)  X(1)  X(2)  X(3)  X(4)  X(5)  X(6)  X(7)  X(8)  X(9)  X(10) X(11) \
    X(12) X(13) X(14) X(15) X(16) X(17) X(18) X(19) X(20) X(21) X(22) X(23) \
    X(24) X(25) X(26) X(27) X(28) X(29) X(30) X(31) X(32) X(33) X(34) X(35) \
    X(36) X(37) X(38) X(39) X(40) X(41) X(42) X(43) X(44) X(45) X(46) X(47)

#define EDECL(p) v2f EA##p, EB##p;

// one quad: 4 pk-FMAs, q-pairs {x,y}/{z,w} are adjacent VGPRs (no splat).
// acc0/acc1 accumulate output column col; acc2/acc3 column col+1.
#define CHUNK(q4, p0, p1) { \
        acc0 += (v2f){q4.x, q4.y} * EA##p0; \
        acc1 += (v2f){q4.z, q4.w} * EA##p1; \
        acc2 += (v2f){q4.x, q4.y} * EB##p0; \
        acc3 += (v2f){q4.z, q4.w} * EB##p1; }

// chunks 8..23 read at top (Q8..Q23); chunks 0..7 use preloaded P0..P7.
#define MATVEC_BODY(qp) \
        v4f Q8  = qp[8],  Q9  = qp[9],  Q10 = qp[10], Q11 = qp[11], \
            Q12 = qp[12], Q13 = qp[13], Q14 = qp[14], Q15 = qp[15]; \
        v4f Q16 = qp[16], Q17 = qp[17], Q18 = qp[18], Q19 = qp[19], \
            Q20 = qp[20], Q21 = qp[21], Q22 = qp[22], Q23 = qp[23]; \
        CHUNK(P0,  0,  1)   CHUNK(P1,  2,  3)  \
        CHUNK(P2,  4,  5)   CHUNK(P3,  6,  7)  \
        CHUNK(P4,  8,  9)   CHUNK(P5,  10, 11) \
        CHUNK(P6,  12, 13)  CHUNK(P7,  14, 15) \
        CHUNK(Q8,  16, 17)  CHUNK(Q9,  18, 19) \
        CHUNK(Q10, 20, 21)  CHUNK(Q11, 22, 23) \
        CHUNK(Q12, 24, 25)  CHUNK(Q13, 26, 27) \
        CHUNK(Q14, 28, 29)  CHUNK(Q15, 30, 31) \
        CHUNK(Q16, 32, 33)  CHUNK(Q17, 34, 35) \
        CHUNK(Q18, 36, 37)  CHUNK(Q19, 38, 39) \
        CHUNK(Q20, 40, 41)  CHUNK(Q21, 42, 43) \
        CHUNK(Q22, 44, 45)  CHUNK(Q23, 46, 47)

    if (fw) {
        // ================= FORWARD: t = 1..511 =================
        // ---- point_score + trans_score (fwd block only) ----
        float ps = 0.f;
        {
            const int* lb = labels_idx + b * Tt;
            #pragma unroll 4
            for (int t = i; t < Tt; t += 64) {
                int i0 = lb[t];
                ps += xbase[t * Ll + i0];
                if (t < Tt - 1) ps += trans[i0 * Ll + lb[t + 1]];
            }
            #pragma unroll
            for (int off = 32; off; off >>= 1) ps += __shfl_xor(ps, off, 64);
        }

        EPAIRS(EDECL)
        // column pairs: EA_p = {E[2p][col], E[2p+1][col]}, EB_p same col+1
#define EINIT(p) { \
        v2f r0 = *reinterpret_cast<const v2f*>(&trans[(2*(p))     * Ll + col]); \
        v2f r1 = *reinterpret_cast<const v2f*>(&trans[(2*(p) + 1) * Ll + col]); \
        EA##p = (v2f){__expf(r0.x), __expf(r1.x)}; \
        EB##p = (v2f){__expf(r0.y), __expf(r1.y)}; \
        asm volatile("" ::: "memory"); }
        EPAIRS(EINIT)
#undef EINIT

        v2f x0 = *reinterpret_cast<const v2f*>(&xbase[col]);
        v2f qv = (v2f){__expf(x0.x), __expf(x0.y)};
        if (i < 48) *reinterpret_cast<v2f*>(&buf[0][col]) = qv;
        asm volatile("" ::: "memory");
        const v4f* q0p = reinterpret_cast<const v4f*>(&buf[0][0]);
        v4f P0 = q0p[0], P1 = q0p[1], P2 = q0p[2], P3 = q0p[3],
            P4 = q0p[4], P5 = q0p[5], P6 = q0p[6], P7 = q0p[7];

        v2f x1 = *reinterpret_cast<const v2f*>(&xbase[1 * Ll + col]);
        v2f ew = (v2f){__expf(x1.x), __expf(x1.y)};
        v2f x2 = *reinterpret_cast<const v2f*>(&xbase[2 * Ll + col]);
        v2f x3 = *reinterpret_cast<const v2f*>(&xbase[3 * Ll + col]);
        v2f x4 = *reinterpret_cast<const v2f*>(&xbase[4 * Ll + col]);
        v2f x5 = *reinterpret_cast<const v2f*>(&xbase[5 * Ll + col]);
        v2f x6 = *reinterpret_cast<const v2f*>(&xbase[6 * Ll + col]);
        v2f x7 = *reinterpret_cast<const v2f*>(&xbase[7 * Ll + col]);

        int Dk = 0;
        #pragma unroll 1
        for (int t = 1; t <= Tt / 2 - 1; ++t) {
            const int rp = (t - 1) & 1, wp = t & 1;
            int k = ((__float_as_int(P0.x) >> 23) & 0xff) - 127;  // wave-uniform
            Dk += k;
            float r = __uint_as_float((unsigned)(127 - k) << 23); // exact 2^-k
            v2f w = ew * r;

            const v4f* qp = reinterpret_cast<const v4f*>(&buf[rp][0]);
            v2f acc0 = {0.f,0.f}, acc1 = {0.f,0.f};
            v2f acc2 = {0.f,0.f}, acc3 = {0.f,0.f};
            MATVEC_BODY(qp)
            v2f va = acc0 + acc1, vb = acc2 + acc3;
            qv = (v2f){va.x + va.y, vb.x + vb.y} * w;

            if (i < 48) *reinterpret_cast<v2f*>(&buf[wp][col]) = qv;
            asm volatile("" ::: "memory");
            const v4f* qn = reinterpret_cast<const v4f*>(&buf[wp][0]);
            P0 = qn[0]; P1 = qn[1]; P2 = qn[2]; P3 = qn[3];
            P4 = qn[4]; P5 = qn[5]; P6 = qn[6]; P7 = qn[7];

            ew = (v2f){__expf(x2.x), __expf(x2.y)};
            x2 = x3; x3 = x4; x4 = x5; x5 = x6; x6 = x7;
            int row = t + 7; if (row > Tt - 1) row = Tt - 1;
            x7 = *reinterpret_cast<const v2f*>(&xbase[row * Ll + col]);
        }
        if (i < 48) *reinterpret_cast<v2f*>(&wsb[col]) = qv;   // Q_511
        if (i == 0) { wsb[192] = __int_as_float(Dk); wsb[194] = ps; }
    } else {
        // ================= BACKWARD: t = 1023..512 =================
        EPAIRS(EDECL)
        // row pairs (contiguous loads): EA_p = {E[col][2p], E[col][2p+1]}
#define EINIT(p) { \
        v2f r0 = *reinterpret_cast<const v2f*>(&trans[col       * Ll + 2*(p)]); \
        v2f r1 = *reinterpret_cast<const v2f*>(&trans[(col + 1) * Ll + 2*(p)]); \
        EA##p = (v2f){__expf(r0.x), __expf(r0.y)}; \
        EB##p = (v2f){__expf(r1.x), __expf(r1.y)}; \
        asm volatile("" ::: "memory"); }
        EPAIRS(EINIT)
#undef EINIT

        // s_1023 = exp(x_1023)
        v2f xT = *reinterpret_cast<const v2f*>(&xbase[(Tt - 1) * Ll + col]);
        v2f s0 = (v2f){__expf(xT.x), __expf(xT.y)};
        if (i < 48) *reinterpret_cast<v2f*>(&buf[0][col]) = s0;
        asm volatile("" ::: "memory");
        const v4f* s0p = reinterpret_cast<const v4f*>(&buf[0][0]);
        v4f P0 = s0p[0], P1 = s0p[1], P2 = s0p[2], P3 = s0p[3],
            P4 = s0p[4], P5 = s0p[5], P6 = s0p[6], P7 = s0p[7];

        v2f xh = *reinterpret_cast<const v2f*>(&xbase[(Tt - 2) * Ll + col]);
        v2f ew = (v2f){__expf(xh.x), __expf(xh.y)};
        v2f x2 = *reinterpret_cast<const v2f*>(&xbase[(Tt - 3) * Ll + col]);
        v2f x3 = *reinterpret_cast<const v2f*>(&xbase[(Tt - 4) * Ll + col]);
        v2f x4 = *reinterpret_cast<const v2f*>(&xbase[(Tt - 5) * Ll + col]);
        v2f x5 = *reinterpret_cast<const v2f*>(&xbase[(Tt - 6) * Ll + col]);
        v2f x6 = *reinterpret_cast<const v2f*>(&xbase[(Tt - 7) * Ll + col]);
        v2f x7 = *reinterpret_cast<const v2f*>(&xbase[(Tt - 8) * Ll + col]);

        int Dk = 0, k = 0;
        v2f qv = (v2f){0.f, 0.f};
        #pragma unroll 1
        for (int t = Tt - 1; t >= Tt / 2; --t) {
            k = ((__float_as_int(P0.x) >> 23) & 0xff) - 127;    // from s_t[0]
            Dk += k;
            float r = __uint_as_float((unsigned)(127 - k) << 23);

            const v4f* qp = reinterpret_cast<const v4f*>(&buf[0][0]);
            v2f acc0 = {0.f,0.f}, acc1 = {0.f,0.f};
            v2f acc2 = {0.f,0.f}, acc3 = {0.f,0.f};
            MATVEC_BODY(qp)
            v2f va = acc0 + acc1, vb = acc2 + acc3;
            qv = (v2f){va.x + va.y, vb.x + vb.y};   // V_{t-1} (stored scale)

            v2f sw = qv * (ew * r);                 // s_{t-1}
            if (i < 48) *reinterpret_cast<v2f*>(&buf[0][col]) = sw;
            asm volatile("" ::: "memory");
            const v4f* sn = reinterpret_cast<const v4f*>(&buf[0][0]);
            P0 = sn[0]; P1 = sn[1]; P2 = sn[2]; P3 = sn[3];
            P4 = sn[4]; P5 = sn[5]; P6 = sn[6]; P7 = sn[7];

            ew = (v2f){__expf(x2.x), __expf(x2.y)};
            x2 = x3; x3 = x4; x4 = x5; x5 = x6; x6 = x7;
            int row = t - 8; if (row < 0) row = 0;
            x7 = *reinterpret_cast<const v2f*>(&xbase[row * Ll + col]);
        }
        Dk -= k;   // FIX: last k was applied only to the never-read s_511
        if (i < 48) *reinterpret_cast<v2f*>(&wsb[96 + col]) = qv;  // V_511
        if (i == 0) wsb[193] = __int_as_float(Dk);
    }
#undef MATVEC_BODY
#undef CHUNK
#undef EDECL
#undef EPAIRS
}

// meeting point: log_norm = log(V_511 . Q_511) + (Dk_f + Dk_b)*ln2
__global__ __launch_bounds__(64, 1) void crf_combine_kernel(
    const float* __restrict__ ws, float* __restrict__ out)
{
    const int b = blockIdx.x;
    const int i = threadIdx.x;
    const int col = (2 * i < Ll) ? 2 * i : (Ll - 2);
    const float* wsb = ws + (size_t)b * WS_STRIDE;

    float d = 0.f;
    if (i < 48) {
        v2f Q = *reinterpret_cast<const v2f*>(&wsb[col]);
        v2f V = *reinterpret_cast<const v2f*>(&wsb[96 + col]);
        d = Q.x * V.x + Q.y * V.y;
    }
    #pragma unroll
    for (int off = 32; off; off >>= 1) d += __shfl_xor(d, off, 64);
    if (i == 0) {
        int Dkf = __float_as_int(wsb[192]);
        int Dkb = __float_as_int(wsb[193]);
        float ps = wsb[194];
        double ln = (double)(Dkf + Dkb) * 0.6931471805599453 + log((double)d);
        out[b] = (float)(ln - (double)ps);
    }
}

extern "C" void kernel_launch(void* const* d_in, const int* in_sizes, int n_in,
                              void* d_out, int out_size, void* d_ws, size_t ws_size,
                              hipStream_t stream) {
    const float* inputs     = (const float*)d_in[0];
    const int*   labels_idx = (const int*)d_in[1];
    const float* trans      = (const float*)d_in[2];
    float*       out        = (float*)d_out;
    float*       ws         = (float*)d_ws;

    crf_scan_kernel<<<dim3(2 * Bb), dim3(64), 0, stream>>>(inputs, labels_idx, trans, ws);
    crf_combine_kernel<<<dim3(Bb), dim3(64), 0, stream>>>(ws, out);
}